// Round 1
// baseline (95.223 us; speedup 1.0000x reference)
//
#include <hip/hip_runtime.h>
#include <hip/hip_bf16.h>
#include <math.h>

#define NC 195            // number of countries
#define ROWS_PER_BLOCK 4  // 256 threads = 4 waves, 1 wave per row

__device__ __forceinline__ float hav_scaled(float lat1, float lon1, float lat2, float lon2) {
    const float d2r = 0.017453292519943295f;
    lat1 *= d2r; lon1 *= d2r; lat2 *= d2r; lon2 *= d2r;
    float sdlat = sinf(0.5f * (lat2 - lat1));
    float sdlon = sinf(0.5f * (lon2 - lon1));
    float a = sdlat * sdlat + cosf(lat1) * cosf(lat2) * sdlon * sdlon;
    a = fminf(fmaxf(a, 0.0f), 1.0f);
    // 2 * R * asin(sqrt(a)) / 500
    return (2.0f * 6371.0f / 500.0f) * asinf(sqrtf(a));
}

// Kernel A: 195x195 pairwise scaled distances
__global__ void dist_kernel(const float* __restrict__ coords, float* __restrict__ distm) {
    int idx = blockIdx.x * 256 + threadIdx.x;
    if (idx >= NC * NC) return;
    int i = idx / NC;
    int j = idx - i * NC;
    distm[idx] = hav_scaled(coords[2 * i], coords[2 * i + 1],
                            coords[2 * j], coords[2 * j + 1]);
}

// Kernel B: one wave per row; per-block partial sum (ce_i + dist_i/500)
__global__ __launch_bounds__(256) void main_kernel(const float* __restrict__ logits,
                                                   const int* __restrict__ target,
                                                   const float* __restrict__ distm,
                                                   float* __restrict__ partials) {
    const int wave = threadIdx.x >> 6;
    const int lane = threadIdx.x & 63;
    const long long row = (long long)blockIdx.x * ROWS_PER_BLOCK + wave;
    const float* __restrict__ rowp = logits + row * NC;

    // coalesced loads: lane, lane+64, lane+128 always valid (191 < 195)
    float x0 = rowp[lane];
    float x1 = rowp[lane + 64];
    float x2 = rowp[lane + 128];
    float x3 = (lane < NC - 192) ? rowp[lane + 192] : -INFINITY;

    // lane-local max + argmax (first occurrence on ties)
    float m = x0; int mi = lane;
    if (x1 > m) { m = x1; mi = lane + 64; }
    if (x2 > m) { m = x2; mi = lane + 128; }
    if (x3 > m) { m = x3; mi = lane + 192; }

    // wave reduce (max, argmax) — tie-break: smaller index
    #pragma unroll
    for (int off = 32; off > 0; off >>= 1) {
        float om = __shfl_xor(m, off);
        int   oi = __shfl_xor(mi, off);
        if (om > m || (om == m && oi < mi)) { m = om; mi = oi; }
    }

    // sum exp(x - m)
    float s = __expf(x0 - m) + __expf(x1 - m) + __expf(x2 - m);
    if (lane < NC - 192) s += __expf(x3 - m);
    #pragma unroll
    for (int off = 32; off > 0; off >>= 1) s += __shfl_xor(s, off);

    __shared__ float part[ROWS_PER_BLOCK];
    if (lane == 0) {
        int t = target[row];
        float tl = rowp[t];                       // L1 hit, row just read
        float ce = (m + __logf(s)) - tl;          // lse - x_t
        part[wave] = ce + distm[mi * NC + t];     // distm pre-scaled by 1/500
    }
    __syncthreads();
    if (threadIdx.x == 0) {
        float v = part[0] + part[1] + part[2] + part[3];
        partials[blockIdx.x] = v;
    }
}

// Kernel C: reduce per-block partials, write mean
__global__ __launch_bounds__(1024) void reduce_kernel(const float* __restrict__ partials,
                                                      int n, float inv_b,
                                                      float* __restrict__ out) {
    float s = 0.0f;
    for (int i = threadIdx.x; i < n; i += 1024) s += partials[i];
    #pragma unroll
    for (int off = 32; off > 0; off >>= 1) s += __shfl_xor(s, off);
    __shared__ float ws[16];
    const int wave = threadIdx.x >> 6;
    const int lane = threadIdx.x & 63;
    if (lane == 0) ws[wave] = s;
    __syncthreads();
    if (threadIdx.x == 0) {
        float tot = 0.0f;
        #pragma unroll
        for (int w = 0; w < 16; ++w) tot += ws[w];
        out[0] = tot * inv_b;
    }
}

extern "C" void kernel_launch(void* const* d_in, const int* in_sizes, int n_in,
                              void* d_out, int out_size, void* d_ws, size_t ws_size,
                              hipStream_t stream) {
    const float* logits = (const float*)d_in[0];
    const int*   target = (const int*)d_in[1];
    const float* coords = (const float*)d_in[2];
    float* out = (float*)d_out;

    const int B = in_sizes[1];                  // 262144
    const int n_blocks = B / ROWS_PER_BLOCK;    // 65536

    // ws layout: [0 .. n_blocks) partials | [n_blocks .. ) dist matrix
    float* partials = (float*)d_ws;
    float* distm = partials + n_blocks;

    dist_kernel<<<(NC * NC + 255) / 256, 256, 0, stream>>>(coords, distm);
    main_kernel<<<n_blocks, 256, 0, stream>>>(logits, target, distm, partials);
    reduce_kernel<<<1, 1024, 0, stream>>>(partials, n_blocks, 1.0f / (float)B, out);
}

// Round 2
// 78.832 us; speedup vs baseline: 1.2079x; 1.2079x over previous
//
#include <hip/hip_runtime.h>
#include <hip/hip_bf16.h>
#include <math.h>

#define NC 195             // number of countries
#define ROWS_PER_BLOCK 16  // 256 threads = 4 waves, 4 rows per wave
#define F4_PER_BLOCK (ROWS_PER_BLOCK * NC / 4)  // 780 float4 = 12480 B, 16B-aligned per block

__device__ __forceinline__ float hav_scaled(float lat1, float lon1, float lat2, float lon2) {
    const float d2r = 0.017453292519943295f;
    lat1 *= d2r; lon1 *= d2r; lat2 *= d2r; lon2 *= d2r;
    float sdlat = sinf(0.5f * (lat2 - lat1));
    float sdlon = sinf(0.5f * (lon2 - lon1));
    float a = sdlat * sdlat + cosf(lat1) * cosf(lat2) * sdlon * sdlon;
    a = fminf(fmaxf(a, 0.0f), 1.0f);
    return (2.0f * 6371.0f / 500.0f) * asinf(sqrtf(a));  // 2*R*asin(sqrt(a))/500
}

// Kernel A: 195x195 pairwise scaled distances (dist[i][j], i=pred, j=target)
__global__ void dist_kernel(const float* __restrict__ coords, float* __restrict__ distm) {
    int idx = blockIdx.x * 256 + threadIdx.x;
    if (idx >= NC * NC) return;
    int i = idx / NC;
    int j = idx - i * NC;
    distm[idx] = hav_scaled(coords[2 * i], coords[2 * i + 1],
                            coords[2 * j], coords[2 * j + 1]);
}

// Kernel B: 16 rows per 256-thread block. Stage chunk to LDS via float4,
// then one wave per 4 rows does argmax + logsumexp out of LDS.
__global__ __launch_bounds__(256) void main_kernel(const float4* __restrict__ logits4,
                                                   const int* __restrict__ target,
                                                   const float* __restrict__ distm,
                                                   float* __restrict__ partials) {
    __shared__ float lds[ROWS_PER_BLOCK * NC];  // 3120 floats = 12480 B
    __shared__ float wpart[4];
    const int t = threadIdx.x;
    const long long base4 = (long long)blockIdx.x * F4_PER_BLOCK;
    float4* lds4 = (float4*)lds;

    // coalesced 16B/lane staging: 780 float4 per block
    lds4[t]       = logits4[base4 + t];
    lds4[t + 256] = logits4[base4 + t + 256];
    lds4[t + 512] = logits4[base4 + t + 512];
    if (t < F4_PER_BLOCK - 768) lds4[t + 768] = logits4[base4 + t + 768];
    __syncthreads();

    const int wave = t >> 6;
    const int lane = t & 63;
    float acc = 0.0f;

    #pragma unroll
    for (int q = 0; q < 4; ++q) {
        const int r = wave * 4 + q;
        const float* __restrict__ rowp = lds + r * NC;
        // stride-1 LDS reads: 2 lanes/bank aliasing = conflict-free
        float x0 = rowp[lane];
        float x1 = rowp[lane + 64];
        float x2 = rowp[lane + 128];
        float x3 = (lane < NC - 192) ? rowp[lane + 192] : -INFINITY;

        float m = x0; int mi = lane;
        if (x1 > m) { m = x1; mi = lane + 64; }
        if (x2 > m) { m = x2; mi = lane + 128; }
        if (x3 > m) { m = x3; mi = lane + 192; }

        #pragma unroll
        for (int off = 32; off > 0; off >>= 1) {
            float om = __shfl_xor(m, off);
            int   oi = __shfl_xor(mi, off);
            if (om > m || (om == m && oi < mi)) { m = om; mi = oi; }
        }

        float s = __expf(x0 - m) + __expf(x1 - m) + __expf(x2 - m);
        if (lane < NC - 192) s += __expf(x3 - m);
        #pragma unroll
        for (int off = 32; off > 0; off >>= 1) s += __shfl_xor(s, off);

        if (lane == 0) {
            long long row = (long long)blockIdx.x * ROWS_PER_BLOCK + r;
            int tg = target[row];
            float ce = (m + __logf(s)) - rowp[tg];     // lse - x_target (from LDS)
            acc += ce + distm[mi * NC + tg];           // distm pre-scaled by 1/500
        }
    }

    if (lane == 0) wpart[wave] = acc;
    __syncthreads();
    if (t == 0) partials[blockIdx.x] = wpart[0] + wpart[1] + wpart[2] + wpart[3];
}

// Kernel C: reduce per-block partials, write mean
__global__ __launch_bounds__(1024) void reduce_kernel(const float* __restrict__ partials,
                                                      int n, float inv_b,
                                                      float* __restrict__ out) {
    float s = 0.0f;
    for (int i = threadIdx.x; i < n; i += 1024) s += partials[i];
    #pragma unroll
    for (int off = 32; off > 0; off >>= 1) s += __shfl_xor(s, off);
    __shared__ float ws[16];
    const int wave = threadIdx.x >> 6;
    const int lane = threadIdx.x & 63;
    if (lane == 0) ws[wave] = s;
    __syncthreads();
    if (threadIdx.x == 0) {
        float tot = 0.0f;
        #pragma unroll
        for (int w = 0; w < 16; ++w) tot += ws[w];
        out[0] = tot * inv_b;
    }
}

extern "C" void kernel_launch(void* const* d_in, const int* in_sizes, int n_in,
                              void* d_out, int out_size, void* d_ws, size_t ws_size,
                              hipStream_t stream) {
    const float* logits = (const float*)d_in[0];
    const int*   target = (const int*)d_in[1];
    const float* coords = (const float*)d_in[2];
    float* out = (float*)d_out;

    const int B = in_sizes[1];                  // 262144
    const int n_blocks = B / ROWS_PER_BLOCK;    // 16384

    float* partials = (float*)d_ws;
    float* distm = partials + n_blocks;

    dist_kernel<<<(NC * NC + 255) / 256, 256, 0, stream>>>(coords, distm);
    main_kernel<<<n_blocks, 256, 0, stream>>>((const float4*)logits, target, distm, partials);
    reduce_kernel<<<1, 1024, 0, stream>>>(partials, n_blocks, 1.0f / (float)B, out);
}

// Round 3
// 49.010 us; speedup vs baseline: 1.9429x; 1.6085x over previous
//
#include <hip/hip_runtime.h>
#include <hip/hip_bf16.h>
#include <math.h>

#define NC 195             // number of countries
#define ROWS_PER_BLOCK 16  // 256 threads = 4 waves; 16 lanes per row, 4 rows/wave
#define F4_PER_BLOCK (ROWS_PER_BLOCK * NC / 4)  // 780 float4 = 12480 B per block

__device__ __forceinline__ float hav_scaled(float lat1, float lon1, float lat2, float lon2) {
    const float d2r = 0.017453292519943295f;
    lat1 *= d2r; lon1 *= d2r; lat2 *= d2r; lon2 *= d2r;
    float sdlat = sinf(0.5f * (lat2 - lat1));
    float sdlon = sinf(0.5f * (lon2 - lon1));
    float a = sdlat * sdlat + cosf(lat1) * cosf(lat2) * sdlon * sdlon;
    a = fminf(fmaxf(a, 0.0f), 1.0f);
    return (2.0f * 6371.0f / 500.0f) * asinf(sqrtf(a));  // 2*R*asin(sqrt(a))/500
}

// Kernel A: 195x195 pairwise scaled distances (dist[i][j], i=pred, j=target)
__global__ void dist_kernel(const float* __restrict__ coords, float* __restrict__ distm) {
    int idx = blockIdx.x * 256 + threadIdx.x;
    if (idx >= NC * NC) return;
    int i = idx / NC;
    int j = idx - i * NC;
    distm[idx] = hav_scaled(coords[2 * i], coords[2 * i + 1],
                            coords[2 * j], coords[2 * j + 1]);
}

// Kernel B: 16 rows per 256-thread block. float4 staging to LDS, then
// 16-lane groups per row: register two-pass (max/argmax, exp-sum),
// 4-level butterfly reduce (offsets 8,4,2,1 stay within the 16-lane group).
__global__ __launch_bounds__(256) void main_kernel(const float4* __restrict__ logits4,
                                                   const int* __restrict__ target,
                                                   const float* __restrict__ distm,
                                                   float* __restrict__ partials) {
    __shared__ float lds[ROWS_PER_BLOCK * NC];  // 12480 B
    __shared__ float wpart[ROWS_PER_BLOCK];
    const int t = threadIdx.x;
    const long long base4 = (long long)blockIdx.x * F4_PER_BLOCK;
    float4* lds4 = (float4*)lds;

    // coalesced 16B/lane staging: 780 float4 per block
    lds4[t]       = logits4[base4 + t];
    lds4[t + 256] = logits4[base4 + t + 256];
    lds4[t + 512] = logits4[base4 + t + 512];
    if (t < F4_PER_BLOCK - 768) lds4[t + 768] = logits4[base4 + t + 768];
    __syncthreads();

    const int lane = t & 63;
    const int u = lane & 15;        // position within 16-lane group
    const int r = t >> 4;           // row within block (0..15)
    const float* __restrict__ rowp = lds + r * NC;

    // load 13 strided elements into registers (u + 16k; k=12 valid iff u<3)
    float x[13];
    #pragma unroll
    for (int k = 0; k < 12; ++k) x[k] = rowp[u + 16 * k];
    x[12] = (u < NC - 192) ? rowp[u + 192] : -INFINITY;

    // pass 1: lane-local max + argmax (first occurrence: ascending k, strict >)
    float m = x[0]; int mi = u;
    #pragma unroll
    for (int k = 1; k < 13; ++k) {
        if (x[k] > m) { m = x[k]; mi = u + 16 * k; }
    }

    // 4-level butterfly over the 16-lane group; tie-break: smaller index
    #pragma unroll
    for (int off = 8; off > 0; off >>= 1) {
        float om = __shfl_xor(m, off);
        int   oi = __shfl_xor(mi, off);
        if (om > m || (om == m && oi < mi)) { m = om; mi = oi; }
    }

    // pass 2: exp-sum (x[12] == -INF contributes exp(-inf)=0)
    float s = 0.0f;
    #pragma unroll
    for (int k = 0; k < 13; ++k) s += __expf(x[k] - m);
    #pragma unroll
    for (int off = 8; off > 0; off >>= 1) s += __shfl_xor(s, off);

    if (u == 0) {
        long long row = (long long)blockIdx.x * ROWS_PER_BLOCK + r;
        int tg = target[row];
        float ce = (m + __logf(s)) - rowp[tg];     // lse - x_target (from LDS)
        wpart[r] = ce + distm[mi * NC + tg];       // distm pre-scaled by 1/500
    }
    __syncthreads();
    if (t == 0) {
        float v = 0.0f;
        #pragma unroll
        for (int i = 0; i < ROWS_PER_BLOCK; ++i) v += wpart[i];
        partials[blockIdx.x] = v;
    }
}

// Kernel C: reduce per-block partials, write mean
__global__ __launch_bounds__(1024) void reduce_kernel(const float* __restrict__ partials,
                                                      int n, float inv_b,
                                                      float* __restrict__ out) {
    float s = 0.0f;
    for (int i = threadIdx.x; i < n; i += 1024) s += partials[i];
    #pragma unroll
    for (int off = 32; off > 0; off >>= 1) s += __shfl_xor(s, off);
    __shared__ float ws[16];
    const int wave = threadIdx.x >> 6;
    const int lane = threadIdx.x & 63;
    if (lane == 0) ws[wave] = s;
    __syncthreads();
    if (threadIdx.x == 0) {
        float tot = 0.0f;
        #pragma unroll
        for (int w = 0; w < 16; ++w) tot += ws[w];
        out[0] = tot * inv_b;
    }
}

extern "C" void kernel_launch(void* const* d_in, const int* in_sizes, int n_in,
                              void* d_out, int out_size, void* d_ws, size_t ws_size,
                              hipStream_t stream) {
    const float* logits = (const float*)d_in[0];
    const int*   target = (const int*)d_in[1];
    const float* coords = (const float*)d_in[2];
    float* out = (float*)d_out;

    const int B = in_sizes[1];                  // 262144
    const int n_blocks = B / ROWS_PER_BLOCK;    // 16384

    float* partials = (float*)d_ws;
    float* distm = partials + n_blocks;

    dist_kernel<<<(NC * NC + 255) / 256, 256, 0, stream>>>(coords, distm);
    main_kernel<<<n_blocks, 256, 0, stream>>>((const float4*)logits, target, distm, partials);
    reduce_kernel<<<1, 1024, 0, stream>>>(partials, n_blocks, 1.0f / (float)B, out);
}

// Round 6
// 46.124 us; speedup vs baseline: 2.0645x; 1.0626x over previous
//
#include <hip/hip_runtime.h>
#include <hip/hip_bf16.h>
#include <math.h>

#define NC 195             // number of countries
#define ROWS_PER_BLOCK 16  // 256 threads = 4 waves; 16 lanes per row, 4 rows/wave
#define F4_PER_BLOCK (ROWS_PER_BLOCK * NC / 4)  // 780 float4 = 12480 B per block

__device__ __forceinline__ float hav_scaled(float lat1, float lon1, float lat2, float lon2) {
    const float d2r = 0.017453292519943295f;
    lat1 *= d2r; lon1 *= d2r; lat2 *= d2r; lon2 *= d2r;
    float sdlat = sinf(0.5f * (lat2 - lat1));
    float sdlon = sinf(0.5f * (lon2 - lon1));
    float a = sdlat * sdlat + cosf(lat1) * cosf(lat2) * sdlon * sdlon;
    a = fminf(fmaxf(a, 0.0f), 1.0f);
    return (2.0f * 6371.0f / 500.0f) * asinf(sqrtf(a));  // 2*R*asin(sqrt(a))/500
}

// Kernel A: 195x195 pairwise scaled distances (dist[i][j], i=pred, j=target)
__global__ void dist_kernel(const float* __restrict__ coords, float* __restrict__ distm) {
    int idx = blockIdx.x * 256 + threadIdx.x;
    if (idx >= NC * NC) return;
    int i = idx / NC;
    int j = idx - i * NC;
    distm[idx] = hav_scaled(coords[2 * i], coords[2 * i + 1],
                            coords[2 * j], coords[2 * j + 1]);
}

// Kernel B: 16 rows per 256-thread block. float4 VGPR staging to LDS, then
// 16-lane groups per row: register two-pass softmax stats + 4-level butterfly.
__global__ __launch_bounds__(256) void main_kernel(const float4* __restrict__ logits4,
                                                   const int* __restrict__ target,
                                                   const float* __restrict__ distm,
                                                   float* __restrict__ partials) {
    __shared__ float lds[ROWS_PER_BLOCK * NC];  // 12480 B
    __shared__ int tgt[ROWS_PER_BLOCK];
    __shared__ float wpart[ROWS_PER_BLOCK];
    const int t = threadIdx.x;
    const long long base4 = (long long)blockIdx.x * F4_PER_BLOCK;
    float4* lds4 = (float4*)lds;

    // coalesced 16B/lane staging: 780 float4 per block
    lds4[t]       = logits4[base4 + t];
    lds4[t + 256] = logits4[base4 + t + 256];
    lds4[t + 512] = logits4[base4 + t + 512];
    if (t < F4_PER_BLOCK - 768) lds4[t + 768] = logits4[base4 + t + 768];
    // coalesced target staging (16 contiguous ints)
    if (t < ROWS_PER_BLOCK) tgt[t] = target[(long long)blockIdx.x * ROWS_PER_BLOCK + t];
    __syncthreads();

    const int lane = t & 63;
    const int u = lane & 15;        // position within 16-lane group
    const int r = t >> 4;           // row within block (0..15)
    const float* __restrict__ rowp = lds + r * NC;

    // 13 strided register loads (u + 16k; k=12 valid iff u<3)
    float x[13];
    #pragma unroll
    for (int k = 0; k < 12; ++k) x[k] = rowp[u + 16 * k];
    x[12] = (u < NC - 192) ? rowp[u + 192] : -INFINITY;

    // pass 1: lane-local max + argmax (first occurrence: ascending k, strict >)
    float m = x[0]; int mi = u;
    #pragma unroll
    for (int k = 1; k < 13; ++k) {
        if (x[k] > m) { m = x[k]; mi = u + 16 * k; }
    }

    // 4-level butterfly within the 16-lane group; tie-break: smaller index
    #pragma unroll
    for (int off = 8; off > 0; off >>= 1) {
        float om = __shfl_xor(m, off);
        int   oi = __shfl_xor(mi, off);
        if (om > m || (om == m && oi < mi)) { m = om; mi = oi; }
    }

    // pass 2: exp-sum (x[12] == -INF contributes 0)
    float s = 0.0f;
    #pragma unroll
    for (int k = 0; k < 13; ++k) s += __expf(x[k] - m);
    #pragma unroll
    for (int off = 8; off > 0; off >>= 1) s += __shfl_xor(s, off);

    if (u == 0) {
        int tg = tgt[r];
        float ce = (m + __logf(s)) - rowp[tg];     // lse - x_target (from LDS)
        wpart[r] = ce + distm[mi * NC + tg];       // distm pre-scaled by 1/500
    }
    __syncthreads();
    if (t == 0) {
        float v = 0.0f;
        #pragma unroll
        for (int i = 0; i < ROWS_PER_BLOCK; ++i) v += wpart[i];
        partials[blockIdx.x] = v;
    }
}

// Kernel C1: 64 blocks x 256 threads, each reduces a coalesced 256-slice
__global__ __launch_bounds__(256) void reduce1_kernel(const float* __restrict__ partials,
                                                      float* __restrict__ stage2) {
    float s = partials[blockIdx.x * 256 + threadIdx.x];
    #pragma unroll
    for (int off = 32; off > 0; off >>= 1) s += __shfl_xor(s, off);
    __shared__ float ws[4];
    if ((threadIdx.x & 63) == 0) ws[threadIdx.x >> 6] = s;
    __syncthreads();
    if (threadIdx.x == 0) stage2[blockIdx.x] = ws[0] + ws[1] + ws[2] + ws[3];
}

// Kernel C2: one wave reduces 64 values, writes mean
__global__ void reduce2_kernel(const float* __restrict__ stage2, float inv_b,
                               float* __restrict__ out) {
    float s = stage2[threadIdx.x];
    #pragma unroll
    for (int off = 32; off > 0; off >>= 1) s += __shfl_xor(s, off);
    if (threadIdx.x == 0) out[0] = s * inv_b;
}

extern "C" void kernel_launch(void* const* d_in, const int* in_sizes, int n_in,
                              void* d_out, int out_size, void* d_ws, size_t ws_size,
                              hipStream_t stream) {
    const float* logits = (const float*)d_in[0];
    const int*   target = (const int*)d_in[1];
    const float* coords = (const float*)d_in[2];
    float* out = (float*)d_out;

    const int B = in_sizes[1];                  // 262144
    const int n_blocks = B / ROWS_PER_BLOCK;    // 16384

    // ws layout: partials[16384] | stage2[64] | distm[195*195]
    float* partials = (float*)d_ws;
    float* stage2 = partials + n_blocks;
    float* distm = stage2 + 64;

    dist_kernel<<<(NC * NC + 255) / 256, 256, 0, stream>>>(coords, distm);
    main_kernel<<<n_blocks, 256, 0, stream>>>((const float4*)logits, target, distm, partials);
    reduce1_kernel<<<n_blocks / 256, 256, 0, stream>>>(partials, stage2);
    reduce2_kernel<<<1, 64, 0, stream>>>(stage2, 1.0f / (float)B, out);
}

// Round 7
// 45.595 us; speedup vs baseline: 2.0884x; 1.0116x over previous
//
#include <hip/hip_runtime.h>
#include <hip/hip_bf16.h>
#include <math.h>

#define NC 195                 // number of countries
#define ROWS_PER_CHUNK 16      // per-iteration tile: 16 rows = 780 float4 = 12480 B
#define CHUNKS_PER_BLOCK 8     // block processes 128 rows total
#define BLOCK_ROWS (ROWS_PER_CHUNK * CHUNKS_PER_BLOCK)   // 128
#define F4_PER_CHUNK (ROWS_PER_CHUNK * NC / 4)           // 780

__device__ __forceinline__ float hav_scaled(float lat1, float lon1, float lat2, float lon2) {
    const float d2r = 0.017453292519943295f;
    lat1 *= d2r; lon1 *= d2r; lat2 *= d2r; lon2 *= d2r;
    float sdlat = sinf(0.5f * (lat2 - lat1));
    float sdlon = sinf(0.5f * (lon2 - lon1));
    float a = sdlat * sdlat + cosf(lat1) * cosf(lat2) * sdlon * sdlon;
    a = fminf(fmaxf(a, 0.0f), 1.0f);
    return (2.0f * 6371.0f / 500.0f) * asinf(sqrtf(a));  // 2*R*asin(sqrt(a))/500
}

// Kernel A: 195x195 pairwise scaled distances (dist[i][j], i=pred, j=target)
__global__ void dist_kernel(const float* __restrict__ coords, float* __restrict__ distm) {
    int idx = blockIdx.x * 256 + threadIdx.x;
    if (idx >= NC * NC) return;
    int i = idx / NC;
    int j = idx - i * NC;
    distm[idx] = hav_scaled(coords[2 * i], coords[2 * i + 1],
                            coords[2 * j], coords[2 * j + 1]);
}

// Kernel B: 2048 persistent blocks (8/CU, all resident), 8 chunks of 16 rows each.
// T14 async-STAGE: issue chunk i+1's global loads before computing chunk i, so
// HBM latency hides under the softmax compute + barrier.
__global__ __launch_bounds__(256) void main_kernel(const float4* __restrict__ logits4,
                                                   const int* __restrict__ target,
                                                   const float* __restrict__ distm,
                                                   float* __restrict__ partials) {
    __shared__ float lds[ROWS_PER_CHUNK * NC];   // 12480 B, single buffer
    __shared__ int tgt[BLOCK_ROWS];
    __shared__ float wpart[16];
    const int t = threadIdx.x;
    float4* lds4 = (float4*)lds;

    const long long row0 = (long long)blockIdx.x * BLOCK_ROWS;
    if (t < BLOCK_ROWS) tgt[t] = target[row0 + t];   // one coalesced 128-int read

    const long long base4 = (long long)blockIdx.x * CHUNKS_PER_BLOCK * F4_PER_CHUNK;

    // prologue: stage chunk 0
    float4 n0 = logits4[base4 + t];
    float4 n1 = logits4[base4 + t + 256];
    float4 n2 = logits4[base4 + t + 512];
    float4 n3;
    if (t < F4_PER_CHUNK - 768) n3 = logits4[base4 + t + 768];
    lds4[t] = n0; lds4[t + 256] = n1; lds4[t + 512] = n2;
    if (t < F4_PER_CHUNK - 768) lds4[t + 768] = n3;
    __syncthreads();

    const int u = t & 15;          // lane within 16-lane row group
    const int r = t >> 4;          // row group (0..15)
    const float* __restrict__ rowp = lds + r * NC;
    float acc = 0.0f;

    for (int i = 0; i < CHUNKS_PER_BLOCK; ++i) {
        const bool has_next = (i + 1 < CHUNKS_PER_BLOCK);
        // issue next chunk's loads NOW — in flight during compute below
        if (has_next) {
            const long long nb = base4 + (long long)(i + 1) * F4_PER_CHUNK;
            n0 = logits4[nb + t];
            n1 = logits4[nb + t + 256];
            n2 = logits4[nb + t + 512];
            if (t < F4_PER_CHUNK - 768) n3 = logits4[nb + t + 768];
        }

        // compute current chunk from LDS (validated structure from round 3)
        float x[13];
        #pragma unroll
        for (int k = 0; k < 12; ++k) x[k] = rowp[u + 16 * k];
        x[12] = (u < NC - 192) ? rowp[u + 192] : -INFINITY;

        float m = x[0]; int mi = u;
        #pragma unroll
        for (int k = 1; k < 13; ++k) {
            if (x[k] > m) { m = x[k]; mi = u + 16 * k; }
        }
        #pragma unroll
        for (int off = 8; off > 0; off >>= 1) {
            float om = __shfl_xor(m, off);
            int   oi = __shfl_xor(mi, off);
            if (om > m || (om == m && oi < mi)) { m = om; mi = oi; }
        }
        float s = 0.0f;
        #pragma unroll
        for (int k = 0; k < 13; ++k) s += __expf(x[k] - m);
        #pragma unroll
        for (int off = 8; off > 0; off >>= 1) s += __shfl_xor(s, off);

        if (u == 0) {
            int tg = tgt[i * ROWS_PER_CHUNK + r];
            float ce = (m + __logf(s)) - rowp[tg];   // lse - x_target (LDS)
            acc += ce + distm[mi * NC + tg];         // distm pre-scaled by 1/500
        }
        __syncthreads();                // all groups done reading chunk i
        if (has_next) {
            lds4[t] = n0; lds4[t + 256] = n1; lds4[t + 512] = n2;
            if (t < F4_PER_CHUNK - 768) lds4[t + 768] = n3;
            __syncthreads();            // chunk i+1 visible
        }
    }

    if (u == 0) wpart[r] = acc;
    __syncthreads();
    if (t == 0) {
        float v = 0.0f;
        #pragma unroll
        for (int j = 0; j < 16; ++j) v += wpart[j];
        partials[blockIdx.x] = v;
    }
}

// Kernel C: single block reduces 2048 partials, writes mean
__global__ __launch_bounds__(1024) void reduce_kernel(const float* __restrict__ partials,
                                                      float inv_b, float* __restrict__ out) {
    float s = partials[threadIdx.x] + partials[threadIdx.x + 1024];
    #pragma unroll
    for (int off = 32; off > 0; off >>= 1) s += __shfl_xor(s, off);
    __shared__ float ws[16];
    if ((threadIdx.x & 63) == 0) ws[threadIdx.x >> 6] = s;
    __syncthreads();
    if (threadIdx.x == 0) {
        float tot = 0.0f;
        #pragma unroll
        for (int w = 0; w < 16; ++w) tot += ws[w];
        out[0] = tot * inv_b;
    }
}

extern "C" void kernel_launch(void* const* d_in, const int* in_sizes, int n_in,
                              void* d_out, int out_size, void* d_ws, size_t ws_size,
                              hipStream_t stream) {
    const float* logits = (const float*)d_in[0];
    const int*   target = (const int*)d_in[1];
    const float* coords = (const float*)d_in[2];
    float* out = (float*)d_out;

    const int B = in_sizes[1];               // 262144
    const int n_blocks = B / BLOCK_ROWS;     // 2048

    // ws layout: partials[2048] | distm[195*195]
    float* partials = (float*)d_ws;
    float* distm = partials + n_blocks;

    dist_kernel<<<(NC * NC + 255) / 256, 256, 0, stream>>>(coords, distm);
    main_kernel<<<n_blocks, 256, 0, stream>>>((const float4*)logits, target, distm, partials);
    reduce_kernel<<<1, 1024, 0, stream>>>(partials, 1.0f / (float)B, out);
}